// Round 3
// baseline (76.356 us; speedup 1.0000x reference)
//
#include <hip/hip_runtime.h>

typedef unsigned short u16;
typedef unsigned int u32;
typedef __attribute__((ext_vector_type(8))) short bf16x8;
typedef __attribute__((ext_vector_type(4))) short bf16x4v;
typedef __attribute__((ext_vector_type(4))) float f32x4;

#define NWAYS 10
#define NC 128
#define NHW 1024

__device__ __forceinline__ u16 f2bf(float f) {
  u32 u = __builtin_bit_cast(u32, f);
  return (u16)((u + 0x7fffu + ((u >> 16) & 1u)) >> 16);  // RNE
}

// ---------------- Kernel 0: zero G + msum (645 KB) ----------------
__global__ __launch_bounds__(256) void k_zero(float* __restrict__ p, int n4) {
  int i = blockIdx.x * 256 + threadIdx.x;
  if (i < n4) ((float4*)p)[i] = (float4){0.f, 0.f, 0.f, 0.f};
}

// ---------------- Kernel 1: raw Gram G[j,c,d] += sum_n s_c s_d ; msum[j,c] += sum_n s_c ----
// grid = 10 classes * 20 chunks of 256 n ; block 256
__global__ __launch_bounds__(256) void k_covg(const float* __restrict__ sup,
                                              float* __restrict__ G,
                                              float* __restrict__ msum) {
  __shared__ u16 tile[NC * 256];  // swizzled [c][n], 64 KiB
  int j = blockIdx.x / 20, chunk = blockIdx.x % 20;
  int shot = chunk >> 2, p0 = (chunk & 3) * 256;
  int t = threadIdx.x;
  const float* srcbase = sup + ((size_t)(j * 5 + shot) * NC) * NHW + p0;
  // coalesced staging: wave w loads row it*4+w contiguously (64 x float4)
#pragma unroll 4
  for (int it = 0; it < 32; ++it) {
    int c = it * 4 + (t >> 6);
    int pos = t & 63;
    float4 v = *(const float4*)(srcbase + (size_t)c * NHW + pos * 4);
    int nl = pos * 4;
    int idx = c * 256 + (((nl >> 3) ^ (c & 15)) << 3) + (nl & 7);
    bf16x4v h;
    h[0] = (short)f2bf(v.x); h[1] = (short)f2bf(v.y);
    h[2] = (short)f2bf(v.z); h[3] = (short)f2bf(v.w);
    *(bf16x4v*)&tile[idx] = h;
    float s = v.x + v.y + v.z + v.w;
#pragma unroll
    for (int m = 1; m <= 32; m <<= 1) s += __shfl_xor(s, m, 64);
    if ((t & 63) == 0) atomicAdd(&msum[j * NC + c], s);
  }
  __syncthreads();

  int w = t >> 6, l = t & 63, lr = l & 15, lg = l >> 4;
  f32x4 acc[2][8];
#pragma unroll
  for (int a = 0; a < 2; ++a)
#pragma unroll
    for (int bt = 0; bt < 8; ++bt) acc[a][bt] = (f32x4){0.f, 0.f, 0.f, 0.f};
#pragma unroll 1
  for (int kb = 0; kb < 8; ++kb) {
    int nn = kb * 32 + lg * 8;
    bf16x8 frag[8];
#pragma unroll
    for (int ti = 0; ti < 8; ++ti) {
      int cc = ti * 16 + lr;
      frag[ti] = *(const bf16x8*)&tile[cc * 256 + (((nn >> 3) ^ (cc & 15)) << 3)];
    }
    bf16x8 fa[2];
#pragma unroll
    for (int a = 0; a < 2; ++a) {
      int cc = (2 * w + a) * 16 + lr;
      fa[a] = *(const bf16x8*)&tile[cc * 256 + (((nn >> 3) ^ (cc & 15)) << 3)];
    }
#pragma unroll
    for (int a = 0; a < 2; ++a)
#pragma unroll
      for (int bt = 0; bt < 8; ++bt)
        acc[a][bt] = __builtin_amdgcn_mfma_f32_16x16x32_bf16(fa[a], frag[bt], acc[a][bt], 0, 0, 0);
  }
#pragma unroll
  for (int a = 0; a < 2; ++a)
#pragma unroll
    for (int bt = 0; bt < 8; ++bt)
#pragma unroll
      for (int r = 0; r < 4; ++r) {
        int cr = (2 * w + a) * 16 + lg * 4 + r;  // C/D: row=(lane>>4)*4+reg
        int d = bt * 16 + lr;                    //      col=lane&15
        atomicAdd(&G[((size_t)j * NC + cr) * NC + d], acc[a][bt][r]);
      }
}

// ---------------- Kernel 2: in-place fp32 cov = (G - msum_c*msum_d/N)/(N-1) ----------------
__global__ __launch_bounds__(256) void k_fin(float* __restrict__ G,
                                             const float* __restrict__ msum) {
  int idx = blockIdx.x * 256 + threadIdx.x;  // < 163840
  int j = idx >> 14, rem = idx & 16383, c = rem >> 7, d = rem & 127;
  G[idx] = (G[idx] - msum[j * NC + c] * msum[j * NC + d] * (1.0f / 5120.0f)) * (1.0f / 5119.0f);
}

// ---------------- Kernel 3: weighted q-Gram halves, no atomics, no pre-zero ----
// Wraw[pc][b][c][d] = sum_{p in half pc} w_p q_c q_d ; ss[pc][b][c] = sum q_c^2
// grid = 64 b * 2 halves of 512 p ; block 512 (8 waves); 4 chunks of 128 p each
__global__ __launch_bounds__(512) void k_wgram(const float* __restrict__ q,
                                               const float* __restrict__ cw,
                                               float* __restrict__ Wraw,
                                               float* __restrict__ ss) {
  __shared__ u16 traw[NC * 128];  // 32 KiB [c][128p] swizzled
  __shared__ u16 twgt[NC * 128];  // 32 KiB, w_p-scaled
  __shared__ float ss_loc[NC];
  int bid = blockIdx.x;
  int b = bid >> 1, pc = bid & 1;
  int t = threadIdx.x;
  int w = t >> 6, l = t & 63, lr = l & 15, lg = l >> 4;
  const float* base = q + (size_t)b * NC * NHW + pc * 512;
  const float* cwb = cw + pc * 512;

  float4 v[8];
  auto load_chunk = [&](int chunk) {
#pragma unroll
    for (int it = 0; it < 8; ++it) {
      int idx = it * 512 + t;
      int c = idx >> 5, pos = idx & 31;  // 32 float4 per 128-p row: full-row coalescing
      v[it] = *(const float4*)(base + (size_t)c * NHW + chunk * 128 + pos * 4);
    }
  };
  auto store_chunk = [&](int chunk) {
#pragma unroll
    for (int it = 0; it < 8; ++it) {
      int idx = it * 512 + t;
      int c = idx >> 5, pos = idx & 31;
      float4 vv = v[it];
      float4 wv = *(const float4*)(cwb + chunk * 128 + pos * 4);
      int nl = pos * 4;
      int off = c * 128 + (((nl >> 3) ^ (c & 15)) << 3) + (nl & 7);
      bf16x4v hr, hw;
      hr[0] = (short)f2bf(vv.x); hr[1] = (short)f2bf(vv.y);
      hr[2] = (short)f2bf(vv.z); hr[3] = (short)f2bf(vv.w);
      hw[0] = (short)f2bf(vv.x * wv.x); hw[1] = (short)f2bf(vv.y * wv.y);
      hw[2] = (short)f2bf(vv.z * wv.z); hw[3] = (short)f2bf(vv.w * wv.w);
      *(bf16x4v*)&traw[off] = hr;
      *(bf16x4v*)&twgt[off] = hw;
      float s = vv.x * vv.x + vv.y * vv.y + vv.z * vv.z + vv.w * vv.w;
#pragma unroll
      for (int m = 1; m <= 16; m <<= 1) s += __shfl_xor(s, m, 64);
      if ((l & 31) == 0) ss_loc[c] += s;  // unique writer per (chunk,c): no race
    }
  };

  load_chunk(0);
  if (t < NC) ss_loc[t] = 0.f;
  __syncthreads();  // ss_loc init visible before any +=
  store_chunk(0);
  __syncthreads();

  f32x4 acc[8];
#pragma unroll
  for (int bt = 0; bt < 8; ++bt) acc[bt] = (f32x4){0.f, 0.f, 0.f, 0.f};

#pragma unroll 1
  for (int chunk = 0; chunk < 4; ++chunk) {
    if (chunk < 3) load_chunk(chunk + 1);  // issue-early: HBM hides under MFMA
#pragma unroll
    for (int kb = 0; kb < 4; ++kb) {
      int nn = kb * 32 + lg * 8;
      int arow = w * 16 + lr;  // wave owns 16 rows of W
      bf16x8 fa = *(const bf16x8*)&twgt[arow * 128 + (((nn >> 3) ^ (arow & 15)) << 3)];
      bf16x8 fb[8];
#pragma unroll
      for (int bt = 0; bt < 8; ++bt) {
        int drow = bt * 16 + lr;
        fb[bt] = *(const bf16x8*)&traw[drow * 128 + (((nn >> 3) ^ (drow & 15)) << 3)];
      }
#pragma unroll
      for (int bt = 0; bt < 8; ++bt)
        acc[bt] = __builtin_amdgcn_mfma_f32_16x16x32_bf16(fa, fb[bt], acc[bt], 0, 0, 0);
    }
    __syncthreads();
    if (chunk < 3) { store_chunk(chunk + 1); __syncthreads(); }
  }

  if (t < NC) ss[((size_t)pc * 64 + b) * NC + t] = ss_loc[t];
  float* wb = Wraw + ((size_t)(pc * 64 + b) << 14);
#pragma unroll
  for (int bt = 0; bt < 8; ++bt)
#pragma unroll
    for (int r = 0; r < 4; ++r) {
      int cr = w * 16 + lg * 4 + r;
      int d = bt * 16 + lr;
      wb[cr * 128 + d] = acc[bt][r];  // plain store: this block owns the slab
    }
}

// ---------------- Kernel 4: out[b,j] = sum_cd cov_j[c,d] * rn_c * rn_d * (W0+W1)[b,c,d] ----
// grid = 640 (b*10+j) ; block 256
__global__ __launch_bounds__(256) void k_final(const float* __restrict__ covf,
                                               const float* __restrict__ Wraw,
                                               const float* __restrict__ ss,
                                               float* __restrict__ out) {
  __shared__ float rnl[NC];
  __shared__ float wred[4];
  int bid = blockIdx.x;
  int b = bid / NWAYS, j = bid - b * NWAYS;
  int t = threadIdx.x;
  if (t < NC) rnl[t] = rsqrtf(ss[(size_t)b * NC + t] + ss[(size_t)(64 + b) * NC + t]);
  __syncthreads();
  const float* cj = covf + (size_t)j * 16384;
  const float* w0 = Wraw + ((size_t)b << 14);
  const float* w1 = Wraw + ((size_t)(64 + b) << 14);
  float rd = rnl[t & 127];  // d = idx&127 == t&127, constant per thread
  float sum = 0.f;
#pragma unroll 8
  for (int i = 0; i < 64; ++i) {
    int idx = i * 256 + t;
    sum += cj[idx] * (w0[idx] + w1[idx]) * rnl[idx >> 7];
  }
  sum *= rd;
#pragma unroll
  for (int m = 1; m <= 32; m <<= 1) sum += __shfl_xor(sum, m, 64);
  if ((t & 63) == 0) wred[t >> 6] = sum;
  __syncthreads();
  if (t == 0) out[bid] = wred[0] + wred[1] + wred[2] + wred[3];
}

extern "C" void kernel_launch(void* const* d_in, const int* in_sizes, int n_in,
                              void* d_out, int out_size, void* d_ws, size_t ws_size,
                              hipStream_t stream) {
  (void)in_sizes; (void)n_in; (void)out_size; (void)ws_size;
  const float* q = (const float*)d_in[0];
  const float* sup = (const float*)d_in[1];
  const float* cw = (const float*)d_in[2];
  float* out = (float*)d_out;

  float* G = (float*)d_ws;        // 163840 f32 (becomes fp32 cov in place)
  float* msum = G + 163840;       // 1280 f32
  float* ssb = msum + 1280;       // 2*64*128 f32 (two halves)
  float* Wraw = ssb + 16384;      // 2*64*16384 f32 (two halves, ~8 MB)

  k_zero<<<162, 256, 0, stream>>>(G, (163840 + 1280) / 4);  // G + msum only
  k_covg<<<200, 256, 0, stream>>>(sup, G, msum);
  k_fin<<<640, 256, 0, stream>>>(G, msum);
  k_wgram<<<128, 512, 0, stream>>>(q, cw, Wraw, ssb);
  k_final<<<640, 256, 0, stream>>>(G, Wraw, ssb, out);
}